// Round 13
// baseline (162.796 us; speedup 1.0000x reference)
//
#include <hip/hip_runtime.h>
#include <hip/hip_bf16.h>

#define DIMD 512
#define NSEQ 4096
#define LPAD 4104
#define NCH 12
#define CH 342          // 12 * 342 = 4104 exactly
#define SPLITS 8
#define PT_BK 32

// ws layout (float offsets) — total 4,785,792 floats = 19.1 MB.
#define OFF_P      0u          // 4*256*512 = 524288
#define OFF_CONST  524288u     // 512
#define OFF_Q      524800u     // 4*256 = 1024
#define OFF_AACC   525824u     // 4*4104*4 = 65664  (zeroed inside k_ptable)
#define OFF_PPART  591488u     // 8*1024*512 = 4194304

// ---------------------------------------------------------------------------
// K1: split-K GEMM for P[k*256+v][e] = sum_d emb[v,d]*dw_w[d,k]*pw_w[e,d]
// M=1024 (k,v), N=512 (e), K=512 (d). 64x64 tiles, 8 K-splits of 64, BK=32.
// Also zeroes Aacc (z==0 blocks, disjoint slices) — replaces the memset node.
// NOTE: partials combined by a SEPARATE kernel (k_pcomb). The R6 experiment
// fused the combine via __threadfence last-block pattern: 142us/dispatch
// (device-scope fence forces cross-XCD L2 writeback on MI355X). Kernel
// boundary IS the cheap fence — do not refuse.
// ---------------------------------------------------------------------------
__global__ __launch_bounds__(256) void k_ptable(
    const float* __restrict__ emb, const float* __restrict__ dw_w,
    const float* __restrict__ pw_w, float* __restrict__ Ppart,
    float* __restrict__ Aacc) {
  __shared__ float As[PT_BK][68];   // [d_local][m_row]
  __shared__ float Bs[PT_BK][68];   // [d_local][e_row]
  const int tid = threadIdx.x;
  const int m0 = blockIdx.x * 64;
  const int e0 = blockIdx.y * 64;
  const int z  = blockIdx.z;
  if (z == 0) {   // zero Aacc: 128 blocks x 256 threads, disjoint float4 slices
    const int idx = (blockIdx.y * 16 + blockIdx.x) * 256 + tid;
    if (idx < 16416) reinterpret_cast<float4*>(Aacc)[idx] = make_float4(0.f, 0.f, 0.f, 0.f);
  }
  const int kk = m0 >> 8;           // conv tap, constant per block
  const int v0 = m0 & 255;
  const int srow = tid >> 3;        // 0..31
  const int sd4  = (tid & 7) * 4;   // 0..28
  const int ty = tid >> 4, tx = tid & 15;
  float c[4][4] = {};
  for (int kt = 0; kt < 64; kt += PT_BK) {
    const int d0 = z * 64 + kt;
    const float dw0 = dw_w[(d0 + sd4 + 0) * 4 + kk];
    const float dw1 = dw_w[(d0 + sd4 + 1) * 4 + kk];
    const float dw2 = dw_w[(d0 + sd4 + 2) * 4 + kk];
    const float dw3 = dw_w[(d0 + sd4 + 3) * 4 + kk];
    #pragma unroll
    for (int rr = 0; rr < 2; ++rr) {
      const int row = srow + rr * 32;
      float4 ev = *reinterpret_cast<const float4*>(&emb[(v0 + row) * DIMD + d0 + sd4]);
      As[sd4 + 0][row] = ev.x * dw0;
      As[sd4 + 1][row] = ev.y * dw1;
      As[sd4 + 2][row] = ev.z * dw2;
      As[sd4 + 3][row] = ev.w * dw3;
      float4 bv = *reinterpret_cast<const float4*>(&pw_w[(e0 + row) * DIMD + d0 + sd4]);
      Bs[sd4 + 0][row] = bv.x;
      Bs[sd4 + 1][row] = bv.y;
      Bs[sd4 + 2][row] = bv.z;
      Bs[sd4 + 3][row] = bv.w;
    }
    __syncthreads();
    #pragma unroll
    for (int qq = 0; qq < PT_BK; ++qq) {
      float4 a = *reinterpret_cast<const float4*>(&As[qq][ty * 4]);
      float4 b = *reinterpret_cast<const float4*>(&Bs[qq][tx * 4]);
      c[0][0] += a.x * b.x; c[0][1] += a.x * b.y; c[0][2] += a.x * b.z; c[0][3] += a.x * b.w;
      c[1][0] += a.y * b.x; c[1][1] += a.y * b.y; c[1][2] += a.y * b.z; c[1][3] += a.y * b.w;
      c[2][0] += a.z * b.x; c[2][1] += a.z * b.y; c[2][2] += a.z * b.z; c[2][3] += a.z * b.w;
      c[3][0] += a.w * b.x; c[3][1] += a.w * b.y; c[3][2] += a.w * b.z; c[3][3] += a.w * b.w;
    }
    __syncthreads();
  }
  #pragma unroll
  for (int i = 0; i < 4; ++i) {
    *reinterpret_cast<float4*>(
        &Ppart[(size_t)z * 524288u + (m0 + ty * 4 + i) * DIMD + e0 + tx * 4]) =
        make_float4(c[i][0], c[i][1], c[i][2], c[i][3]);
  }
}

// ---------------------------------------------------------------------------
// K1c: P = sum over splits. Fused extras:
//  - q[row] = dot(P[row,:], score_w)  (per-row wave reduction; row = k*256+v)
//  - blocks 0,1: constv[e] = pw_b[e] + sum_d pw_w[e,d]*dw_b[d]
// ---------------------------------------------------------------------------
__global__ __launch_bounds__(256) void k_pcomb(
    const float* __restrict__ Ppart, float* __restrict__ P,
    const float* __restrict__ pw_w, const float* __restrict__ pw_b,
    const float* __restrict__ dw_b, const float* __restrict__ score_w,
    float* __restrict__ constv, float* __restrict__ q) {
  __shared__ float qred[4];
  const int tid = threadIdx.x;
  const int idx = blockIdx.x * 256 + tid;  // over 131072 float4; 2 rows/block
  const float4* p4 = reinterpret_cast<const float4*>(Ppart);
  float4 a = p4[idx];
  #pragma unroll
  for (int zz = 1; zz < SPLITS; ++zz) {
    float4 v = p4[(size_t)zz * 131072u + idx];
    a.x += v.x; a.y += v.y; a.z += v.z; a.w += v.w;
  }
  reinterpret_cast<float4*>(P)[idx] = a;
  float4 sw = reinterpret_cast<const float4*>(score_w)[idx & 127];
  float part = a.x * sw.x + a.y * sw.y + a.z * sw.z + a.w * sw.w;
  for (int off = 32; off > 0; off >>= 1) part += __shfl_down(part, off);
  if ((tid & 63) == 0) qred[tid >> 6] = part;
  __syncthreads();
  if (tid == 0)   q[blockIdx.x * 2 + 0] = qred[0] + qred[1];
  if (tid == 128) q[blockIdx.x * 2 + 1] = qred[2] + qred[3];
  if (blockIdx.x < 2) {
    const int e = blockIdx.x * 256 + tid;
    float acc = pw_b[e];
    const float4* pr = reinterpret_cast<const float4*>(&pw_w[e * DIMD]);
    const float4* db = reinterpret_cast<const float4*>(dw_b);
    for (int d4 = 0; d4 < DIMD / 4; ++d4) {
      float4 w = pr[d4]; float4 bb = db[d4];
      acc += w.x * bb.x + w.y * bb.y + w.z * bb.z + w.w * bb.w;
    }
    constv[e] = acc;
  }
}

// ---------------------------------------------------------------------------
// K5: streaming attention with s computed INLINE. Per block: rebuild t (from
// the 4KB q-table) and s for its 256 i-rows and its 342-row j-chunk in LDS;
// then exp(si.sj) accumulation with atomics into Aacc.
// sim in [0,1] => exp never overflows => no max tracking needed.
// Z not accumulated: rows of s sum to 1, so Z_i = sum_k Aacc_ik.
// Inner-loop exp via exp2 (si pre-scaled by log2 e).
// ---------------------------------------------------------------------------
__global__ __launch_bounds__(256) void k_attn(
    const int* __restrict__ x, const float* __restrict__ q,
    const float* __restrict__ constv, const float* __restrict__ score_w,
    const float* __restrict__ score_b_p, float* __restrict__ Aacc) {
  __shared__ float qlds[1024];
  __shared__ float tli[264];   // t for [i0-2, i0+258]
  __shared__ float tlj[348];   // t for [j0-2, j0+344]
  __shared__ float4 sch[CH];
  __shared__ float c0red[2];
  const int b = blockIdx.z;
  const int c = blockIdx.y;
  const int i0 = blockIdx.x * 256;
  const int j0 = c * CH;
  const int tid = threadIdx.x;
  reinterpret_cast<float4*>(qlds)[tid] = reinterpret_cast<const float4*>(q)[tid];
  if (tid < 128) {
    float4 cv = reinterpret_cast<const float4*>(constv)[tid];
    float4 sw = reinterpret_cast<const float4*>(score_w)[tid];
    float part = cv.x * sw.x + cv.y * sw.y + cv.z * sw.z + cv.w * sw.w;
    for (int off = 32; off > 0; off >>= 1) part += __shfl_down(part, off);
    if ((tid & 63) == 0) c0red[tid >> 6] = part;
  }
  __syncthreads();
  const float c0 = c0red[0] + c0red[1];
  const int* xb = &x[b * NSEQ];
  auto tval = [&](int l) -> float {
    if ((unsigned)l >= (unsigned)NSEQ) return 0.f;
    float acc = c0;
    #pragma unroll
    for (int k = 0; k < 4; ++k) {
      const int pos = l + k;
      if (pos < NSEQ) acc += qlds[(k << 8) + xb[pos]];
    }
    return acc;
  };
  for (int idx = tid; idx < 261; idx += 256) tli[idx] = tval(i0 - 2 + idx);
  for (int idx = tid; idx < 347; idx += 256) tlj[idx] = tval(j0 - 2 + idx);
  __syncthreads();
  const float sb = score_b_p[0];
  for (int idx = tid; idx < CH; idx += 256) {
    const int l = j0 + idx;
    #define TJ(j) tlj[(j) - j0 + 2]
    float p0 = TJ(l) + sb;
    int j2 = l & ~1;
    float p1 = (TJ(j2) + TJ(j2 + 1)) * 0.5f + sb;
    int j3 = (l / 3) * 3;
    float p2 = (TJ(j3) + TJ(j3 + 1) + TJ(j3 + 2)) * (1.0f / 3.0f) + sb;
    int j4 = l & ~3;
    float p3 = (TJ(j4) + TJ(j4 + 1) + TJ(j4 + 2) + TJ(j4 + 3)) * 0.25f + sb;
    #undef TJ
    float mx = fmaxf(fmaxf(p0, p1), fmaxf(p2, p3));
    float e0 = __expf(p0 - mx), e1 = __expf(p1 - mx);
    float e2 = __expf(p2 - mx), e3 = __expf(p3 - mx);
    float inv = 1.0f / (e0 + e1 + e2 + e3);
    sch[idx] = make_float4(e0 * inv, e1 * inv, e2 * inv, e3 * inv);
  }
  const int i = i0 + tid;
  float4 si;
  {
    const int l = i;
    #define TI(j) tli[(j) - i0 + 2]
    float p0 = TI(l) + sb;
    int j2 = l & ~1;
    float p1 = (TI(j2) + TI(j2 + 1)) * 0.5f + sb;
    int j3 = (l / 3) * 3;
    float p2 = (TI(j3) + TI(j3 + 1) + TI(j3 + 2)) * (1.0f / 3.0f) + sb;
    int j4 = l & ~3;
    float p3 = (TI(j4) + TI(j4 + 1) + TI(j4 + 2) + TI(j4 + 3)) * 0.25f + sb;
    #undef TI
    float mx = fmaxf(fmaxf(p0, p1), fmaxf(p2, p3));
    float e0 = __expf(p0 - mx), e1 = __expf(p1 - mx);
    float e2 = __expf(p2 - mx), e3 = __expf(p3 - mx);
    float inv = 1.0f / (e0 + e1 + e2 + e3);
    si = make_float4(e0 * inv, e1 * inv, e2 * inv, e3 * inv);
  }
  __syncthreads();
  if (i >= LPAD) return;
  const float LOG2E = 1.4426950408889634f;
  const float s2x = si.x * LOG2E, s2y = si.y * LOG2E;
  const float s2z = si.z * LOG2E, s2w = si.w * LOG2E;
  float a0x = 0.f, a0y = 0.f, a0z = 0.f, a0w = 0.f;
  float a1x = 0.f, a1y = 0.f, a1z = 0.f, a1w = 0.f;
  #pragma unroll 3
  for (int jj = 0; jj < CH; jj += 2) {
    float4 u = sch[jj];
    float4 v = sch[jj + 1];
    float d0 = s2x * u.x + s2y * u.y + s2z * u.z + s2w * u.w;
    float d1 = s2x * v.x + s2y * v.y + s2z * v.z + s2w * v.w;
    float e0 = __builtin_amdgcn_exp2f(d0);
    float e1 = __builtin_amdgcn_exp2f(d1);
    a0x += e0 * u.x; a0y += e0 * u.y; a0z += e0 * u.z; a0w += e0 * u.w;
    a1x += e1 * v.x; a1y += e1 * v.y; a1z += e1 * v.z; a1w += e1 * v.w;
  }
  float* aa = &Aacc[((size_t)(b * LPAD) + i) * 4];
  atomicAdd(aa + 0, a0x + a1x);
  atomicAdd(aa + 1, a0y + a1y);
  atomicAdd(aa + 2, a0z + a1z);
  atomicAdd(aa + 3, a0w + a1w);
}

// ---------------------------------------------------------------------------
// K7: final recombine + DS-mean, y recomputed from the P gather.
// 8 groups per 128-thread block; overlapping bands -> 36 distinct rows
// (vs 8x8=64 if non-shared).
// ---------------------------------------------------------------------------
__global__ __launch_bounds__(128) void k_out(
    const int* __restrict__ x, const float* __restrict__ P,
    const float* __restrict__ constv, const float* __restrict__ Aacc,
    float* __restrict__ out) {
  const int b = blockIdx.y;
  const int g0 = blockIdx.x * 8;
  const int tl = threadIdx.x;
  const int R0 = 4 * g0 - 2;
  __shared__ float coef[8][36];
  for (int idx = tl; idx < 8 * 36; idx += 128) (&coef[0][0])[idx] = 0.f;
  __syncthreads();
  if (tl < 8) {
    const int g = g0 + tl;
    const float4* a4 = reinterpret_cast<const float4*>(Aacc) + (size_t)b * LPAD;
    for (int dl = 0; dl < 4; ++dl) {
      const int l = 4 * g + dl;
      float4 av = a4[l];
      float inv = 1.0f / (av.x + av.y + av.z + av.w);
      float sk[4] = {av.x * inv, av.y * inv, av.z * inv, av.w * inv};
      for (int k = 0; k < 4; ++k) {
        const int bs = k + 1;
        const int j0 = (l / bs) * bs;
        const float wv = sk[k] / (float)(bs * 4);
        for (int jj = 0; jj < bs; ++jj) coef[tl][j0 + jj - R0] += wv;
      }
    }
  }
  __syncthreads();
  const int* xb = &x[b * NSEQ];
  const float4 cv = reinterpret_cast<const float4*>(constv)[tl];
  float4 acc[8];
  #pragma unroll
  for (int gi = 0; gi < 8; ++gi) acc[gi] = make_float4(0.f, 0.f, 0.f, 0.f);
  for (int r = 0; r < 36; ++r) {
    const int row = R0 + r;
    if ((unsigned)row >= (unsigned)NSEQ) continue;   // pad rows have y = 0
    float csum = 0.f;
    #pragma unroll
    for (int gi = 0; gi < 8; ++gi) csum += coef[gi][r];
    if (csum == 0.f) continue;
    float yx = cv.x, yy = cv.y, yz = cv.z, yw = cv.w;
    #pragma unroll
    for (int k = 0; k < 4; ++k) {
      const int pos = row + k;
      if (pos < NSEQ) {
        const int tok = xb[pos];
        const float4 pv = *reinterpret_cast<const float4*>(
            &P[((unsigned)(k << 8) + tok) * DIMD + tl * 4]);
        yx += pv.x; yy += pv.y; yz += pv.z; yw += pv.w;
      }
    }
    #pragma unroll
    for (int gi = 0; gi < 8; ++gi) {
      const float cg = coef[gi][r];
      acc[gi].x += cg * yx; acc[gi].y += cg * yy;
      acc[gi].z += cg * yz; acc[gi].w += cg * yw;
    }
  }
  float4* o = reinterpret_cast<float4*>(out) + ((size_t)(b * 1024) + g0) * 128 + tl;
  #pragma unroll
  for (int gi = 0; gi < 8; ++gi) o[gi * 128] = acc[gi];
}

extern "C" void kernel_launch(void* const* d_in, const int* in_sizes, int n_in,
                              void* d_out, int out_size, void* d_ws, size_t ws_size,
                              hipStream_t stream) {
  const int* x = (const int*)d_in[0];
  const float* emb = (const float*)d_in[1];
  const float* dw_w = (const float*)d_in[2];
  const float* dw_b = (const float*)d_in[3];
  const float* pw_w = (const float*)d_in[4];
  const float* pw_b = (const float*)d_in[5];
  const float* score_w = (const float*)d_in[6];
  const float* score_b = (const float*)d_in[7];
  float* out = (float*)d_out;
  float* ws = (float*)d_ws;
  float* P      = ws + OFF_P;
  float* constv = ws + OFF_CONST;
  float* q      = ws + OFF_Q;
  float* Aacc   = ws + OFF_AACC;
  float* Ppart  = ws + OFF_PPART;

  k_ptable<<<dim3(16, 8, SPLITS), 256, 0, stream>>>(emb, dw_w, pw_w, Ppart, Aacc);
  k_pcomb<<<512, 256, 0, stream>>>(Ppart, P, pw_w, pw_b, dw_b, score_w, constv, q);
  k_attn<<<dim3(17, NCH, 4), 256, 0, stream>>>(x, q, constv, score_w, score_b, Aacc);
  k_out<<<dim3(128, 4), 128, 0, stream>>>(x, P, constv, Aacc, out);
}

// Round 14
// 147.600 us; speedup vs baseline: 1.1030x; 1.1030x over previous
//
#include <hip/hip_runtime.h>
#include <hip/hip_bf16.h>

#define DIMD 512
#define NSEQ 4096
#define LPAD 4104
#define NCH 12
#define CH 342          // 12 * 342 = 4104 exactly
#define SPLITS 8
#define PT_BK 32

// ws layout (float offsets) — total 4,785,792 floats = 19.1 MB.
#define OFF_P      0u          // 4*256*512 = 524288
#define OFF_CONST  524288u     // 512
#define OFF_Q      524800u     // 4*256 = 1024
#define OFF_AACC   525824u     // 4*4104*4 = 65664  (zeroed inside k_ptable)
#define OFF_PPART  591488u     // 8*1024*512 = 4194304

// ---------------------------------------------------------------------------
// K1: split-K GEMM for P[k*256+v][e] = sum_d emb[v,d]*dw_w[d,k]*pw_w[e,d]
// M=1024 (k,v), N=512 (e), K=512 (d). 64x64 tiles, 8 K-splits of 64, BK=32.
// Also zeroes Aacc (z==0 blocks, disjoint slices) — replaces the memset node.
// NOTE: partials combined by a SEPARATE kernel (k_pcomb). The R6 experiment
// fused the combine via __threadfence last-block pattern: 142us/dispatch
// (device-scope fence forces cross-XCD L2 writeback on MI355X). Kernel
// boundary IS the cheap fence — do not refuse.
// ---------------------------------------------------------------------------
__global__ __launch_bounds__(256) void k_ptable(
    const float* __restrict__ emb, const float* __restrict__ dw_w,
    const float* __restrict__ pw_w, float* __restrict__ Ppart,
    float* __restrict__ Aacc) {
  __shared__ float As[PT_BK][68];   // [d_local][m_row]
  __shared__ float Bs[PT_BK][68];   // [d_local][e_row]
  const int tid = threadIdx.x;
  const int m0 = blockIdx.x * 64;
  const int e0 = blockIdx.y * 64;
  const int z  = blockIdx.z;
  if (z == 0) {   // zero Aacc: 128 blocks x 256 threads, disjoint float4 slices
    const int idx = (blockIdx.y * 16 + blockIdx.x) * 256 + tid;
    if (idx < 16416) reinterpret_cast<float4*>(Aacc)[idx] = make_float4(0.f, 0.f, 0.f, 0.f);
  }
  const int kk = m0 >> 8;           // conv tap, constant per block
  const int v0 = m0 & 255;
  const int srow = tid >> 3;        // 0..31
  const int sd4  = (tid & 7) * 4;   // 0..28
  const int ty = tid >> 4, tx = tid & 15;
  float c[4][4] = {};
  for (int kt = 0; kt < 64; kt += PT_BK) {
    const int d0 = z * 64 + kt;
    const float dw0 = dw_w[(d0 + sd4 + 0) * 4 + kk];
    const float dw1 = dw_w[(d0 + sd4 + 1) * 4 + kk];
    const float dw2 = dw_w[(d0 + sd4 + 2) * 4 + kk];
    const float dw3 = dw_w[(d0 + sd4 + 3) * 4 + kk];
    #pragma unroll
    for (int rr = 0; rr < 2; ++rr) {
      const int row = srow + rr * 32;
      float4 ev = *reinterpret_cast<const float4*>(&emb[(v0 + row) * DIMD + d0 + sd4]);
      As[sd4 + 0][row] = ev.x * dw0;
      As[sd4 + 1][row] = ev.y * dw1;
      As[sd4 + 2][row] = ev.z * dw2;
      As[sd4 + 3][row] = ev.w * dw3;
      float4 bv = *reinterpret_cast<const float4*>(&pw_w[(e0 + row) * DIMD + d0 + sd4]);
      Bs[sd4 + 0][row] = bv.x;
      Bs[sd4 + 1][row] = bv.y;
      Bs[sd4 + 2][row] = bv.z;
      Bs[sd4 + 3][row] = bv.w;
    }
    __syncthreads();
    #pragma unroll
    for (int qq = 0; qq < PT_BK; ++qq) {
      float4 a = *reinterpret_cast<const float4*>(&As[qq][ty * 4]);
      float4 b = *reinterpret_cast<const float4*>(&Bs[qq][tx * 4]);
      c[0][0] += a.x * b.x; c[0][1] += a.x * b.y; c[0][2] += a.x * b.z; c[0][3] += a.x * b.w;
      c[1][0] += a.y * b.x; c[1][1] += a.y * b.y; c[1][2] += a.y * b.z; c[1][3] += a.y * b.w;
      c[2][0] += a.z * b.x; c[2][1] += a.z * b.y; c[2][2] += a.z * b.z; c[2][3] += a.z * b.w;
      c[3][0] += a.w * b.x; c[3][1] += a.w * b.y; c[3][2] += a.w * b.z; c[3][3] += a.w * b.w;
    }
    __syncthreads();
  }
  #pragma unroll
  for (int i = 0; i < 4; ++i) {
    *reinterpret_cast<float4*>(
        &Ppart[(size_t)z * 524288u + (m0 + ty * 4 + i) * DIMD + e0 + tx * 4]) =
        make_float4(c[i][0], c[i][1], c[i][2], c[i][3]);
  }
}

// ---------------------------------------------------------------------------
// K1c: P = sum over splits. Fused extras:
//  - q[row] = dot(P[row,:], score_w)  (per-row wave reduction; row = k*256+v)
//  - blocks 0,1: constv[e] = pw_b[e] + sum_d pw_w[e,d]*dw_b[d]
// ---------------------------------------------------------------------------
__global__ __launch_bounds__(256) void k_pcomb(
    const float* __restrict__ Ppart, float* __restrict__ P,
    const float* __restrict__ pw_w, const float* __restrict__ pw_b,
    const float* __restrict__ dw_b, const float* __restrict__ score_w,
    float* __restrict__ constv, float* __restrict__ q) {
  __shared__ float qred[4];
  const int tid = threadIdx.x;
  const int idx = blockIdx.x * 256 + tid;  // over 131072 float4; 2 rows/block
  const float4* p4 = reinterpret_cast<const float4*>(Ppart);
  float4 a = p4[idx];
  #pragma unroll
  for (int zz = 1; zz < SPLITS; ++zz) {
    float4 v = p4[(size_t)zz * 131072u + idx];
    a.x += v.x; a.y += v.y; a.z += v.z; a.w += v.w;
  }
  reinterpret_cast<float4*>(P)[idx] = a;
  float4 sw = reinterpret_cast<const float4*>(score_w)[idx & 127];
  float part = a.x * sw.x + a.y * sw.y + a.z * sw.z + a.w * sw.w;
  for (int off = 32; off > 0; off >>= 1) part += __shfl_down(part, off);
  if ((tid & 63) == 0) qred[tid >> 6] = part;
  __syncthreads();
  if (tid == 0)   q[blockIdx.x * 2 + 0] = qred[0] + qred[1];
  if (tid == 128) q[blockIdx.x * 2 + 1] = qred[2] + qred[3];
  if (blockIdx.x < 2) {
    const int e = blockIdx.x * 256 + tid;
    float acc = pw_b[e];
    const float4* pr = reinterpret_cast<const float4*>(&pw_w[e * DIMD]);
    const float4* db = reinterpret_cast<const float4*>(dw_b);
    for (int d4 = 0; d4 < DIMD / 4; ++d4) {
      float4 w = pr[d4]; float4 bb = db[d4];
      acc += w.x * bb.x + w.y * bb.y + w.z * bb.z + w.w * bb.w;
    }
    constv[e] = acc;
  }
}

// ---------------------------------------------------------------------------
// K5: streaming attention with s computed INLINE. Per block: rebuild t (from
// the 4KB q-table) and s for its 256 i-rows and its 342-row j-chunk in LDS;
// then exp(si.sj) accumulation with atomics into Aacc.
// sim in [0,1] => exp never overflows => no max tracking needed.
// Z not accumulated: rows of s sum to 1, so Z_i = sum_k Aacc_ik.
// Inner-loop exp via exp2 (si pre-scaled by log2 e).
// ---------------------------------------------------------------------------
__global__ __launch_bounds__(256) void k_attn(
    const int* __restrict__ x, const float* __restrict__ q,
    const float* __restrict__ constv, const float* __restrict__ score_w,
    const float* __restrict__ score_b_p, float* __restrict__ Aacc) {
  __shared__ float qlds[1024];
  __shared__ float tli[264];   // t for [i0-2, i0+258]
  __shared__ float tlj[348];   // t for [j0-2, j0+344]
  __shared__ float4 sch[CH];
  __shared__ float c0red[2];
  const int b = blockIdx.z;
  const int c = blockIdx.y;
  const int i0 = blockIdx.x * 256;
  const int j0 = c * CH;
  const int tid = threadIdx.x;
  reinterpret_cast<float4*>(qlds)[tid] = reinterpret_cast<const float4*>(q)[tid];
  if (tid < 128) {
    float4 cv = reinterpret_cast<const float4*>(constv)[tid];
    float4 sw = reinterpret_cast<const float4*>(score_w)[tid];
    float part = cv.x * sw.x + cv.y * sw.y + cv.z * sw.z + cv.w * sw.w;
    for (int off = 32; off > 0; off >>= 1) part += __shfl_down(part, off);
    if ((tid & 63) == 0) c0red[tid >> 6] = part;
  }
  __syncthreads();
  const float c0 = c0red[0] + c0red[1];
  const int* xb = &x[b * NSEQ];
  auto tval = [&](int l) -> float {
    if ((unsigned)l >= (unsigned)NSEQ) return 0.f;
    float acc = c0;
    #pragma unroll
    for (int k = 0; k < 4; ++k) {
      const int pos = l + k;
      if (pos < NSEQ) acc += qlds[(k << 8) + xb[pos]];
    }
    return acc;
  };
  for (int idx = tid; idx < 261; idx += 256) tli[idx] = tval(i0 - 2 + idx);
  for (int idx = tid; idx < 347; idx += 256) tlj[idx] = tval(j0 - 2 + idx);
  __syncthreads();
  const float sb = score_b_p[0];
  for (int idx = tid; idx < CH; idx += 256) {
    const int l = j0 + idx;
    #define TJ(j) tlj[(j) - j0 + 2]
    float p0 = TJ(l) + sb;
    int j2 = l & ~1;
    float p1 = (TJ(j2) + TJ(j2 + 1)) * 0.5f + sb;
    int j3 = (l / 3) * 3;
    float p2 = (TJ(j3) + TJ(j3 + 1) + TJ(j3 + 2)) * (1.0f / 3.0f) + sb;
    int j4 = l & ~3;
    float p3 = (TJ(j4) + TJ(j4 + 1) + TJ(j4 + 2) + TJ(j4 + 3)) * 0.25f + sb;
    #undef TJ
    float mx = fmaxf(fmaxf(p0, p1), fmaxf(p2, p3));
    float e0 = __expf(p0 - mx), e1 = __expf(p1 - mx);
    float e2 = __expf(p2 - mx), e3 = __expf(p3 - mx);
    float inv = 1.0f / (e0 + e1 + e2 + e3);
    sch[idx] = make_float4(e0 * inv, e1 * inv, e2 * inv, e3 * inv);
  }
  const int i = i0 + tid;
  float4 si;
  {
    const int l = i;
    #define TI(j) tli[(j) - i0 + 2]
    float p0 = TI(l) + sb;
    int j2 = l & ~1;
    float p1 = (TI(j2) + TI(j2 + 1)) * 0.5f + sb;
    int j3 = (l / 3) * 3;
    float p2 = (TI(j3) + TI(j3 + 1) + TI(j3 + 2)) * (1.0f / 3.0f) + sb;
    int j4 = l & ~3;
    float p3 = (TI(j4) + TI(j4 + 1) + TI(j4 + 2) + TI(j4 + 3)) * 0.25f + sb;
    #undef TI
    float mx = fmaxf(fmaxf(p0, p1), fmaxf(p2, p3));
    float e0 = __expf(p0 - mx), e1 = __expf(p1 - mx);
    float e2 = __expf(p2 - mx), e3 = __expf(p3 - mx);
    float inv = 1.0f / (e0 + e1 + e2 + e3);
    si = make_float4(e0 * inv, e1 * inv, e2 * inv, e3 * inv);
  }
  __syncthreads();
  if (i >= LPAD) return;
  const float LOG2E = 1.4426950408889634f;
  const float s2x = si.x * LOG2E, s2y = si.y * LOG2E;
  const float s2z = si.z * LOG2E, s2w = si.w * LOG2E;
  float a0x = 0.f, a0y = 0.f, a0z = 0.f, a0w = 0.f;
  float a1x = 0.f, a1y = 0.f, a1z = 0.f, a1w = 0.f;
  #pragma unroll 3
  for (int jj = 0; jj < CH; jj += 2) {
    float4 u = sch[jj];
    float4 v = sch[jj + 1];
    float d0 = s2x * u.x + s2y * u.y + s2z * u.z + s2w * u.w;
    float d1 = s2x * v.x + s2y * v.y + s2z * v.z + s2w * v.w;
    float e0 = __builtin_amdgcn_exp2f(d0);
    float e1 = __builtin_amdgcn_exp2f(d1);
    a0x += e0 * u.x; a0y += e0 * u.y; a0z += e0 * u.z; a0w += e0 * u.w;
    a1x += e1 * v.x; a1y += e1 * v.y; a1z += e1 * v.z; a1w += e1 * v.w;
  }
  float* aa = &Aacc[((size_t)(b * LPAD) + i) * 4];
  atomicAdd(aa + 0, a0x + a1x);
  atomicAdd(aa + 1, a0y + a1y);
  atomicAdd(aa + 2, a0z + a1z);
  atomicAdd(aa + 3, a0w + a1w);
}

// ---------------------------------------------------------------------------
// K7: final recombine + DS-mean, y recomputed from the P gather.
// 4 groups per 128-thread block; the block touches only 20 distinct rows.
// (R13 tried 8 groups/block: grid halved to 1 wave/SIMD on a latency-bound
// gather -> 162.8us total, +14 vs R12. Keep 4/block.)
// ---------------------------------------------------------------------------
__global__ __launch_bounds__(128) void k_out(
    const int* __restrict__ x, const float* __restrict__ P,
    const float* __restrict__ constv, const float* __restrict__ Aacc,
    float* __restrict__ out) {
  const int b = blockIdx.y;
  const int g0 = blockIdx.x * 4;
  const int tl = threadIdx.x;
  const int R0 = 4 * g0 - 2;
  __shared__ float coef[4][20];
  if (tl < 80) (&coef[0][0])[tl] = 0.f;
  __syncthreads();
  if (tl < 4) {
    const int g = g0 + tl;
    const float4* a4 = reinterpret_cast<const float4*>(Aacc) + (size_t)b * LPAD;
    for (int dl = 0; dl < 4; ++dl) {
      const int l = 4 * g + dl;
      float4 av = a4[l];
      float inv = 1.0f / (av.x + av.y + av.z + av.w);
      float sk[4] = {av.x * inv, av.y * inv, av.z * inv, av.w * inv};
      for (int k = 0; k < 4; ++k) {
        const int bs = k + 1;
        const int j0 = (l / bs) * bs;
        const float wv = sk[k] / (float)(bs * 4);
        for (int jj = 0; jj < bs; ++jj) coef[tl][j0 + jj - R0] += wv;
      }
    }
  }
  __syncthreads();
  const int* xb = &x[b * NSEQ];
  const float4 cv = reinterpret_cast<const float4*>(constv)[tl];
  float4 acc0 = {0.f, 0.f, 0.f, 0.f}, acc1 = {0.f, 0.f, 0.f, 0.f};
  float4 acc2 = {0.f, 0.f, 0.f, 0.f}, acc3 = {0.f, 0.f, 0.f, 0.f};
  for (int r = 0; r < 20; ++r) {
    const int row = R0 + r;
    if ((unsigned)row >= (unsigned)NSEQ) continue;   // pad rows have y = 0
    const float c0 = coef[0][r], c1 = coef[1][r];
    const float c2 = coef[2][r], c3 = coef[3][r];
    if (c0 + c1 + c2 + c3 == 0.f) continue;
    float yx = cv.x, yy = cv.y, yz = cv.z, yw = cv.w;
    #pragma unroll
    for (int k = 0; k < 4; ++k) {
      const int pos = row + k;
      if (pos < NSEQ) {
        const int tok = xb[pos];
        const float4 pv = *reinterpret_cast<const float4*>(
            &P[((unsigned)(k << 8) + tok) * DIMD + tl * 4]);
        yx += pv.x; yy += pv.y; yz += pv.z; yw += pv.w;
      }
    }
    acc0.x += c0 * yx; acc0.y += c0 * yy; acc0.z += c0 * yz; acc0.w += c0 * yw;
    acc1.x += c1 * yx; acc1.y += c1 * yy; acc1.z += c1 * yz; acc1.w += c1 * yw;
    acc2.x += c2 * yx; acc2.y += c2 * yy; acc2.z += c2 * yz; acc2.w += c2 * yw;
    acc3.x += c3 * yx; acc3.y += c3 * yy; acc3.z += c3 * yz; acc3.w += c3 * yw;
  }
  float4* o = reinterpret_cast<float4*>(out) + ((size_t)(b * 1024) + g0) * 128 + tl;
  o[0 * 128] = acc0;
  o[1 * 128] = acc1;
  o[2 * 128] = acc2;
  o[3 * 128] = acc3;
}

extern "C" void kernel_launch(void* const* d_in, const int* in_sizes, int n_in,
                              void* d_out, int out_size, void* d_ws, size_t ws_size,
                              hipStream_t stream) {
  const int* x = (const int*)d_in[0];
  const float* emb = (const float*)d_in[1];
  const float* dw_w = (const float*)d_in[2];
  const float* dw_b = (const float*)d_in[3];
  const float* pw_w = (const float*)d_in[4];
  const float* pw_b = (const float*)d_in[5];
  const float* score_w = (const float*)d_in[6];
  const float* score_b = (const float*)d_in[7];
  float* out = (float*)d_out;
  float* ws = (float*)d_ws;
  float* P      = ws + OFF_P;
  float* constv = ws + OFF_CONST;
  float* q      = ws + OFF_Q;
  float* Aacc   = ws + OFF_AACC;
  float* Ppart  = ws + OFF_PPART;

  k_ptable<<<dim3(16, 8, SPLITS), 256, 0, stream>>>(emb, dw_w, pw_w, Ppart, Aacc);
  k_pcomb<<<512, 256, 0, stream>>>(Ppart, P, pw_w, pw_b, dw_b, score_w, constv, q);
  k_attn<<<dim3(17, NCH, 4), 256, 0, stream>>>(x, q, constv, score_w, score_b, Aacc);
  k_out<<<dim3(256, 4), 128, 0, stream>>>(x, P, constv, Aacc, out);
}